// Round 15
// baseline (315.760 us; speedup 1.0000x reference)
//
#include <hip/hip_runtime.h>
#include <math.h>

#define B_ 4
#define T_ 2048
#define C_ 1024
#define D_ 64
#define N_ 16384
#define K_ 32
#define SCALE 0.03125f   // 1/sqrt(1024)
#define NEGINF -3.402823e38f

typedef __attribute__((ext_vector_type(8))) short short8_t;  // 8 bf16 (4 VGPRs)
typedef __attribute__((ext_vector_type(4))) float f32x4;

__device__ __forceinline__ unsigned short f2bf(float x) {
    union { float f; unsigned u; } a; a.f = x;
    const unsigned r = a.u + 0x7fffu + ((a.u >> 16) & 1u);   // round-nearest-even
    return (unsigned short)(r >> 16);
}
__device__ __forceinline__ float bf2f(unsigned short h) {
    union { unsigned u; float f; } a; a.u = ((unsigned)h) << 16;
    return a.f;
}

// ---------------------------------------------------------------------------
// Pack [Wq|Wk|Wv] into bf16 hi/lo MFMA B-fragments (unchanged)
// ---------------------------------------------------------------------------
__global__ __launch_bounds__(256) void wfrag_prep_kernel(
    const float* __restrict__ Wq, const float* __restrict__ Wk,
    const float* __restrict__ Wv,
    unsigned short* __restrict__ whfrag, unsigned short* __restrict__ wlfrag)
{
    const int tid = threadIdx.x;
    const int w = tid >> 6, lane = tid & 63;
    const int id = blockIdx.x * 4 + w;          // 0..383
    const int ct = id >> 5, ks = id & 31;
    const float* W = (ct < 4) ? Wq : (ct < 8) ? Wk : Wv;
    const int colw = (ct & 3) * 16 + (lane & 15);
    const int k0 = ks * 32 + (lane >> 4) * 8;
    unsigned short* dh = whfrag + (size_t)id * 512 + (size_t)lane * 8;
    unsigned short* dl = wlfrag + (size_t)id * 512 + (size_t)lane * 8;
    #pragma unroll
    for (int j = 0; j < 8; ++j) {
        const float val = W[(size_t)(k0 + j) * D_ + colw];
        const unsigned short h = f2bf(val);
        dh[j] = h;
        dl[j] = f2bf(val - bf2f(h));
    }
}

// ---------------------------------------------------------------------------
// QKV projection via MFMA (unchanged from round 13)
// ---------------------------------------------------------------------------
__global__ __launch_bounds__(256) void qkv_mfma_kernel(
    const float* __restrict__ x,
    const unsigned short* __restrict__ whfrag, const unsigned short* __restrict__ wlfrag,
    const float* __restrict__ bq, const float* __restrict__ bk,
    const float* __restrict__ bv,
    float* __restrict__ q, float* __restrict__ k, float* __restrict__ v)
{
    __shared__ unsigned short xh[32][136], xl[32][136];
    const int tid = threadIdx.x;
    const int w = tid >> 6, lane = tid & 63;
    const int row0 = blockIdx.x * 32;
    const int rt = w & 1;
    const int ct0 = (w >> 1) * 6;

    f32x4 acc[6];
    #pragma unroll
    for (int i = 0; i < 6; ++i) {
        const int ct = ct0 + i;
        const float* bias = (ct < 4) ? bq : (ct < 8) ? bk : bv;
        const float bb = bias[(ct & 3) * 16 + (lane & 15)];
        acc[i] = (f32x4){bb, bb, bb, bb};
    }

    for (int kc = 0; kc < 8; ++kc) {
        __syncthreads();
        #pragma unroll
        for (int p = 0; p < 4; ++p) {
            const int fi = tid + p * 256;
            const int row = fi >> 5, c4 = fi & 31;
            const float4 xv =
                *(const float4*)(x + (size_t)(row0 + row) * C_ + kc * 128 + c4 * 4);
            const unsigned short h0 = f2bf(xv.x), h1 = f2bf(xv.y);
            const unsigned short h2 = f2bf(xv.z), h3 = f2bf(xv.w);
            xh[row][c4 * 4 + 0] = h0;  xl[row][c4 * 4 + 0] = f2bf(xv.x - bf2f(h0));
            xh[row][c4 * 4 + 1] = h1;  xl[row][c4 * 4 + 1] = f2bf(xv.y - bf2f(h1));
            xh[row][c4 * 4 + 2] = h2;  xl[row][c4 * 4 + 2] = f2bf(xv.z - bf2f(h2));
            xh[row][c4 * 4 + 3] = h3;  xl[row][c4 * 4 + 3] = f2bf(xv.w - bf2f(h3));
        }
        __syncthreads();
        #pragma unroll
        for (int ks = 0; ks < 4; ++ks) {
            const int aoff = ks * 32 + (lane >> 4) * 8;
            const short8_t ah = *(const short8_t*)&xh[rt * 16 + (lane & 15)][aoff];
            const short8_t al = *(const short8_t*)&xl[rt * 16 + (lane & 15)][aoff];
            #pragma unroll
            for (int i = 0; i < 6; ++i) {
                const size_t tb = ((size_t)(ct0 + i) * 32 + kc * 4 + ks) * 512
                                + (size_t)lane * 8;
                const short8_t wh = *(const short8_t*)(whfrag + tb);
                const short8_t wl = *(const short8_t*)(wlfrag + tb);
                acc[i] = __builtin_amdgcn_mfma_f32_16x16x32_bf16(ah, wh, acc[i], 0, 0, 0);
                acc[i] = __builtin_amdgcn_mfma_f32_16x16x32_bf16(ah, wl, acc[i], 0, 0, 0);
                acc[i] = __builtin_amdgcn_mfma_f32_16x16x32_bf16(al, wh, acc[i], 0, 0, 0);
            }
        }
    }

    #pragma unroll
    for (int i = 0; i < 6; ++i) {
        const int ct = ct0 + i;
        float* o = (ct < 4) ? q : (ct < 8) ? k : v;
        const int col = (ct & 3) * 16 + (lane & 15);
        const int rbase = row0 + rt * 16 + (lane >> 4) * 4;
        #pragma unroll
        for (int r = 0; r < 4; ++r)
            o[(size_t)(rbase + r) * D_ + col] = acc[i][r];
    }
}

// ---------------------------------------------------------------------------
// Pack mem_keys into bf16 hi/lo MFMA B-fragment layout (unchanged)
// ---------------------------------------------------------------------------
__global__ __launch_bounds__(256) void kfrag_prep_kernel(
    const float* __restrict__ keys, unsigned short* __restrict__ khi,
    unsigned short* __restrict__ klo)
{
    const int tid = threadIdx.x;
    const int lane = tid & 63;
    const int ks = (tid >> 6) & 1;
    const int b  = blockIdx.x >> 9;
    const int nt = ((blockIdx.x & 511) << 1) | (tid >> 7);
    const int key = nt * 16 + (lane & 15);
    const float* src = keys + ((size_t)b * N_ + key) * D_ + ks * 32 + (lane >> 4) * 8;
    const size_t o = (((size_t)b * 1024 + nt) * 2 + ks) * 512 + (size_t)lane * 8;
    #pragma unroll
    for (int j = 0; j < 8; ++j) {
        const float xv = src[j];
        const unsigned short h = f2bf(xv);
        khi[o + j] = h;
        klo[o + j] = f2bf(xv - bf2f(h));
    }
}

// ---------------------------------------------------------------------------
// Pack causal K and V into bf16 MFMA fragment buffers (unchanged)
// ---------------------------------------------------------------------------
__global__ __launch_bounds__(256) void causal_prep_kernel(
    const float* __restrict__ k, const float* __restrict__ v,
    unsigned short* __restrict__ kcfrag, unsigned short* __restrict__ vfrag)
{
    __shared__ float vtile[64][68];
    const int tid = threadIdx.x;
    const int b = blockIdx.x >> 5;
    const int n64 = blockIdx.x & 31;
    const int w = tid >> 6, lane = tid & 63;
    const int q16 = lane & 15, g = lane >> 4;

    const float4* in4 = (const float4*)(v + ((size_t)b * T_ + n64 * 64) * D_);
    #pragma unroll
    for (int p = 0; p < 4; ++p) {
        const int fi = tid + p * 256;
        const int row = fi >> 4, c4 = fi & 15;
        *(float4*)&vtile[row][c4 * 4] = in4[fi];
    }

    {
        const int key = (n64 * 4 + w) * 16 + q16;
        #pragma unroll
        for (int ks = 0; ks < 2; ++ks) {
            const float* src = k + ((size_t)b * T_ + key) * D_ + ks * 32 + g * 8;
            const float4 x0 = *(const float4*)(src);
            const float4 x1 = *(const float4*)(src + 4);
            unsigned short* dst = kcfrag
                + ((((size_t)b * 128 + n64 * 4 + w) * 2 + ks) * 512) + (size_t)lane * 8;
            dst[0] = f2bf(x0.x); dst[1] = f2bf(x0.y); dst[2] = f2bf(x0.z); dst[3] = f2bf(x0.w);
            dst[4] = f2bf(x1.x); dst[5] = f2bf(x1.y); dst[6] = f2bf(x1.z); dst[7] = f2bf(x1.w);
        }
    }
    __syncthreads();

    #pragma unroll
    for (int ks = 0; ks < 2; ++ks) {
        unsigned short* dst = vfrag
            + ((((size_t)b * 32 + n64) * 8 + ks * 4 + w) * 512) + (size_t)lane * 8;
        #pragma unroll
        for (int j = 0; j < 8; ++j)
            dst[j] = f2bf(vtile[ks * 32 + g * 8 + j][w * 16 + q16]);
    }
}

// ---------------------------------------------------------------------------
// Causal flash attention (round 7 + work-reversal: heaviest blocks first)
// ---------------------------------------------------------------------------
__global__ __launch_bounds__(256) void causal_flash_kernel(
    const float* __restrict__ qg,
    const unsigned short* __restrict__ kcfrag, const unsigned short* __restrict__ vfrag,
    float* __restrict__ outc)
{
    __shared__ unsigned int plds[64][36];
    __shared__ float po[4][64][17];
    __shared__ float pml[4][2][16];
    const int tid = threadIdx.x;
    const int w = tid >> 6, lane = tid & 63;
    const int q16 = lane & 15, g = lane >> 4;
    const int b = blockIdx.x >> 7;
    const int qt = 127 - (blockIdx.x & 127);   // big-work blocks dispatch first
    const int t0 = qt * 16;
    const int qglob = t0 + q16;
    const int n64 = (qt >> 2) + 1;

    short8_t qf[2];
    #pragma unroll
    for (int ks = 0; ks < 2; ++ks) {
        const float* src = qg + ((size_t)b * T_ + qglob) * D_ + ks * 32 + g * 8;
        const float4 x0 = *(const float4*)(src);
        const float4 x1 = *(const float4*)(src + 4);
        qf[ks][0] = (short)f2bf(x0.x); qf[ks][1] = (short)f2bf(x0.y);
        qf[ks][2] = (short)f2bf(x0.z); qf[ks][3] = (short)f2bf(x0.w);
        qf[ks][4] = (short)f2bf(x1.x); qf[ks][5] = (short)f2bf(x1.y);
        qf[ks][6] = (short)f2bf(x1.z); qf[ks][7] = (short)f2bf(x1.w);
    }

    float m = -1.0e30f, l = 0.f;
    f32x4 o[4];
    #pragma unroll
    for (int dt = 0; dt < 4; ++dt) o[dt] = (f32x4){0.f, 0.f, 0.f, 0.f};

    const int qrow = w * 16 + q16;

    for (int n = w; n < n64; n += 4) {
        short8_t kf[4][2];
        #pragma unroll
        for (int a = 0; a < 4; ++a)
            #pragma unroll
            for (int ks = 0; ks < 2; ++ks)
                kf[a][ks] = *(const short8_t*)(kcfrag
                    + ((((size_t)b * 128 + n * 4 + a) * 2 + ks) * 512) + (size_t)lane * 8);
        f32x4 st[4];
        #pragma unroll
        for (int a = 0; a < 4; ++a) {
            st[a] = (f32x4){0.f, 0.f, 0.f, 0.f};
            st[a] = __builtin_amdgcn_mfma_f32_16x16x32_bf16(kf[a][0], qf[0], st[a], 0, 0, 0);
            st[a] = __builtin_amdgcn_mfma_f32_16x16x32_bf16(kf[a][1], qf[1], st[a], 0, 0, 0);
        }

        float sv[4][4];
        float pm = -1.0e30f;
        #pragma unroll
        for (int a = 0; a < 4; ++a)
            #pragma unroll
            for (int r = 0; r < 4; ++r) {
                const int kk = n * 64 + a * 16 + g * 4 + r;
                float x = st[a][r] * SCALE;
                x = (kk <= qglob) ? x : -1.0e31f;
                sv[a][r] = x;
                pm = fmaxf(pm, x);
            }
        pm = fmaxf(pm, __shfl_xor(pm, 16));
        pm = fmaxf(pm, __shfl_xor(pm, 32));
        const float mn = fmaxf(m, pm);
        const float al = __expf(m - mn);
        float rs = 0.f;
        float ev[4][4];
        #pragma unroll
        for (int a = 0; a < 4; ++a)
            #pragma unroll
            for (int r = 0; r < 4; ++r) {
                const float e = __expf(sv[a][r] - mn);
                ev[a][r] = e;
                rs += e;
            }
        rs += __shfl_xor(rs, 16);
        rs += __shfl_xor(rs, 32);
        l = l * al + rs;
        m = mn;
        #pragma unroll
        for (int dt = 0; dt < 4; ++dt) o[dt] *= al;

        #pragma unroll
        for (int a = 0; a < 4; ++a)
            #pragma unroll
            for (int rp = 0; rp < 2; ++rp)
                plds[qrow][a * 8 + g * 2 + rp] =
                    (unsigned)f2bf(ev[a][2 * rp]) | ((unsigned)f2bf(ev[a][2 * rp + 1]) << 16);
        #pragma unroll
        for (int ks = 0; ks < 2; ++ks) {
            const short8_t pf = *(const short8_t*)&plds[qrow][ks * 16 + g * 4];
            #pragma unroll
            for (int dt = 0; dt < 4; ++dt) {
                const short8_t vf = *(const short8_t*)(vfrag
                    + ((((size_t)b * 32 + n) * 8 + ks * 4 + dt) * 512) + (size_t)lane * 8);
                o[dt] = __builtin_amdgcn_mfma_f32_16x16x32_bf16(vf, pf, o[dt], 0, 0, 0);
            }
        }
    }

    #pragma unroll
    for (int dt = 0; dt < 4; ++dt)
        #pragma unroll
        for (int r = 0; r < 4; ++r)
            po[w][dt * 16 + g * 4 + r][q16] = o[dt][r];
    if (g == 0) { pml[w][0][q16] = m; pml[w][1][q16] = l; }
    __syncthreads();

    {
        const int q = tid & 15;
        const int dgrp = tid >> 4;
        float mw[4], lw[4];
        #pragma unroll
        for (int ww = 0; ww < 4; ++ww) { mw[ww] = pml[ww][0][q]; lw[ww] = pml[ww][1][q]; }
        const float M = fmaxf(fmaxf(mw[0], mw[1]), fmaxf(mw[2], mw[3]));
        float wgt[4], L = 0.f;
        #pragma unroll
        for (int ww = 0; ww < 4; ++ww) {
            wgt[ww] = __expf(mw[ww] - M);
            L += lw[ww] * wgt[ww];
        }
        const float inv = 1.0f / L;
        float4 res;
        float* rp = &res.x;
        #pragma unroll
        for (int i = 0; i < 4; ++i) {
            const int d = dgrp * 4 + i;
            float s = 0.f;
            #pragma unroll
            for (int ww = 0; ww < 4; ++ww) s += po[ww][d][q] * wgt[ww];
            rp[i] = s * inv;
        }
        *(float4*)(outc + ((size_t)b * T_ + t0 + q) * D_ + dgrp * 4) = res;
    }
}

// ---------------------------------------------------------------------------
// kNN v12: CH=2 (512-key LDS buffers, exactly 64 KB) -> 32 barriers (was 64);
// max-first ballots (1 ballot per 256-key half per query instead of 4).
// TQ=16, 512 threads, grid 512.  Warmup = exact top-32 of first 256 keys,
// then candidate-stream everything else.  Fused epilogue.
// ---------------------------------------------------------------------------
__global__ __launch_bounds__(512) void knn_mfma_kernel(
    const float* __restrict__ qg,
    const unsigned short* __restrict__ khi, const unsigned short* __restrict__ klo,
    const float* __restrict__ mem_vals, const float* __restrict__ outc,
    const float* __restrict__ gate, float* __restrict__ outp)
{
    __shared__ float sc_lds[2][16][512];   // 64 KB exactly
    const int tid = threadIdx.x;
    const int w = tid >> 6, lane = tid & 63;     // 8 waves
    const int bid = blockIdx.x;                  // 512 blocks
    const int b  = (bid & 7) >> 1;               // batch -> XCD pair
    const int qt = ((bid >> 3) << 1) | (bid & 1); // 0..127
    const int t0 = qt * 16;

    short8_t qh[2], ql[2];
    {
        const int qrow = t0 + (lane & 15);
        const float* qs = qg + ((size_t)b * T_ + qrow) * D_ + (lane >> 4) * 8;
        #pragma unroll
        for (int ks2 = 0; ks2 < 2; ++ks2) {
            #pragma unroll
            for (int j = 0; j < 8; ++j) {
                const float xv = qs[ks2 * 32 + j];
                const unsigned short h = f2bf(xv);
                qh[ks2][j] = (short)h;
                ql[ks2][j] = (short)f2bf(xv - bf2f(h));
            }
        }
    }

    const int qrow4 = (lane >> 4) * 4;
    const int c16 = lane & 15;

    // per 512-key buffer: wave w owns tiles tl = w + 8*tt, tt = 0..3
#define LOADFRAGS(CC, KH, KL)                                                  \
    {                                                                          \
        _Pragma("unroll")                                                      \
        for (int tt = 0; tt < 4; ++tt) {                                       \
            const int tl = w + 8 * tt;                                         \
            const size_t kb = (((size_t)b * 1024 + (size_t)(CC) * 32 + tl) * 2) * 512 \
                            + (size_t)lane * 8;                                \
            KH[tt][0] = *(const short8_t*)(khi + kb);                          \
            KH[tt][1] = *(const short8_t*)(khi + kb + 512);                    \
            KL[tt][0] = *(const short8_t*)(klo + kb);                          \
            KL[tt][1] = *(const short8_t*)(klo + kb + 512);                    \
        }                                                                      \
    }

#define MFMAWRITE(BUF, KH, KL)                                                 \
    {                                                                          \
        _Pragma("unroll")                                                      \
        for (int tt = 0; tt < 4; ++tt) {                                       \
            const int tl = w + 8 * tt;                                         \
            f32x4 acc = {0.f, 0.f, 0.f, 0.f};                                  \
            acc = __builtin_amdgcn_mfma_f32_16x16x32_bf16(qh[0], KH[tt][0], acc, 0, 0, 0); \
            acc = __builtin_amdgcn_mfma_f32_16x16x32_bf16(qh[1], KH[tt][1], acc, 0, 0, 0); \
            acc = __builtin_amdgcn_mfma_f32_16x16x32_bf16(qh[0], KL[tt][0], acc, 0, 0, 0); \
            acc = __builtin_amdgcn_mfma_f32_16x16x32_bf16(qh[1], KL[tt][1], acc, 0, 0, 0); \
            acc = __builtin_amdgcn_mfma_f32_16x16x32_bf16(ql[0], KH[tt][0], acc, 0, 0, 0); \
            acc = __builtin_amdgcn_mfma_f32_16x16x32_bf16(ql[1], KH[tt][1], acc, 0, 0, 0); \
            const int col = tl * 16 + c16;                                     \
            _Pragma("unroll")                                                  \
            for (int r = 0; r < 4; ++r) sc_lds[BUF][qrow4 + r][col] = acc[r];  \
        }                                                                      \
    }

    // stream one 4-score group (values in S4[0..3], lane-local), keys
    // base = (CC<<9) + (HALF<<8) + lane*4 + j
#define STREAM4(S4, CC, HALF, QQ)                                              \
    {                                                                          \
        const float m01 = fmaxf(S4[0], S4[1]);                                 \
        const float m23 = fmaxf(S4[2], S4[3]);                                 \
        unsigned mask4 = (S4[0] > t32[QQ] ? 1u : 0u) | (S4[1] > t32[QQ] ? 2u : 0u) \
                       | (S4[2] > t32[QQ] ? 4u : 0u) | (S4[3] > t32[QQ] ? 8u : 0u); \
        unsigned long long bb = __ballot(fmaxf(m01, m23) > t32[QQ]);           \
        while (bb) {                                                           \
            const int L = __ffsll(bb) - 1;                                     \
            bb &= bb - 1;                                                      \
            const unsigned mL = (unsigned)__shfl((int)mask4, L);               \
            _Pragma("unroll")                                                  \
            for (int j = 0; j < 4; ++j) {                                      \
                if ((mL >> j) & 1u) {                                          \
                    const float xv = __shfl(S4[j], L);                         \
                    const int xi = ((CC) << 9) + ((HALF) << 8) + (L << 2) + j; \
                    const unsigned long long gb =                              \
                        __ballot((lane < K_) && (rv[QQ] > xv));                \
                    const int pos = __popcll(gb);                              \
                    const float sv = __shfl_up(rv[QQ], 1);                     \
                    const int   si = __shfl_up(rid_[QQ], 1);                   \
                    if (lane > pos)       { rv[QQ] = sv; rid_[QQ] = si; }      \
                    else if (lane == pos) { rv[QQ] = xv; rid_[QQ] = xi; }      \
                }                                                              \
            }                                                                  \
        }                                                                      \
    }

    float rv[2];  int rid_[2];  float t32[2];
    #pragma unroll
    for (int qq = 0; qq < 2; ++qq) {
        rv[qq] = NEGINF; rid_[qq] = 0x7fffffff; t32[qq] = NEGINF;
    }

    // prologue: buffer 0 (keys 0..511) scored
    {
        short8_t kh[4][2], kl[4][2];
        LOADFRAGS(0, kh, kl);
        MFMAWRITE(0, kh, kl);
    }
    __syncthreads();

    for (int c = 0; c < 32; ++c) {
        short8_t kh[4][2], kl[4][2];
        if (c < 31) LOADFRAGS(c + 1, kh, kl);

        if (c == 0) {
            // warmup: exact sorted top-32 of keys 0..255 (half 0), per query
            #pragma unroll
            for (int qq = 0; qq < 2; ++qq) {
                float s4[4];
                *(float4*)s4 = *(const float4*)&sc_lds[0][w * 2 + qq][lane * 4];
                float lmax = NEGINF; int lslot = 0;
                #pragma unroll
                for (int j = 0; j < 4; ++j)
                    if (s4[j] > lmax) { lmax = s4[j]; lslot = j; }
                for (int it = 0; it < 32; ++it) {
                    float wm = lmax;
                    #pragma unroll
                    for (int off = 32; off; off >>= 1)
                        wm = fmaxf(wm, __shfl_xor(wm, off));
                    const unsigned long long bal = __ballot(lmax == wm);
                    const int winner = __ffsll((unsigned long long)bal) - 1;
                    const int wslot  = __shfl(lslot, winner);
                    const int widx   = (winner << 2) + (wslot & 3);
                    const unsigned long long gb = __ballot((lane < K_) && (rv[qq] > wm));
                    const int pos = __popcll(gb);
                    const float sv = __shfl_up(rv[qq], 1);
                    const int   si = __shfl_up(rid_[qq], 1);
                    if (lane > pos)       { rv[qq] = sv; rid_[qq] = si; }
                    else if (lane == pos) { rv[qq] = wm; rid_[qq] = widx; }
                    if (lane == winner) {
                        float nm = NEGINF; int ns = 0;
                        #pragma unroll
                        for (int j = 0; j < 4; ++j) {
                            const float vj = (j == lslot) ? NEGINF : s4[j];
                            s4[j] = vj;
                            if (vj > nm) { nm = vj; ns = j; }
                        }
                        lmax = nm; lslot = ns;
                    }
                }
                t32[qq] = __shfl(rv[qq], 31);
                // half 1 (keys 256..511) streamed
                float s4b[4];
                *(float4*)s4b = *(const float4*)&sc_lds[0][w * 2 + qq][256 + lane * 4];
                STREAM4(s4b, 0, 1, qq)
                t32[qq] = __shfl(rv[qq], 31);
            }
        } else {
            #pragma unroll
            for (int qq = 0; qq < 2; ++qq) {
                float s4a[4], s4b[4];
                *(float4*)s4a = *(const float4*)&sc_lds[c & 1][w * 2 + qq][lane * 4];
                *(float4*)s4b = *(const float4*)&sc_lds[c & 1][w * 2 + qq][256 + lane * 4];
                STREAM4(s4a, c, 0, qq)
                STREAM4(s4b, c, 1, qq)
                t32[qq] = __shfl(rv[qq], 31);   // once per buffer
            }
        }

        if (c < 31) MFMAWRITE((c + 1) & 1, kh, kl);
        __syncthreads();
    }

#undef LOADFRAGS
#undef MFMAWRITE
#undef STREAM4

    // ---- epilogue: softmax over top-32, gather V, gated combine
    const float gv = gate[0];
    const float* vb = mem_vals + (size_t)b * N_ * D_;
    #pragma unroll
    for (int qq = 0; qq < 2; ++qq) {
        const float m = __shfl(rv[qq], 0);
        float wgt = (lane < K_) ? __expf((rv[qq] - m) * SCALE) : 0.f;
        float ssum = wgt;
        #pragma unroll
        for (int off = 32; off; off >>= 1) ssum += __shfl_xor(ssum, off);
        float acc = 0.f;
        for (int i = 0; i < K_; ++i) {
            const float wi = __shfl(wgt, i);
            const int   ii = __shfl(rid_[qq], i);
            acc += wi * vb[(size_t)ii * D_ + lane];
        }
        const size_t o = ((size_t)(b * T_ + t0 + w * 2 + qq)) * D_ + lane;
        outp[o] = outc[o] * gv + (acc / ssum) * (1.f - gv);
    }
}

extern "C" void kernel_launch(void* const* d_in, const int* in_sizes, int n_in,
                              void* d_out, int out_size, void* d_ws, size_t ws_size,
                              hipStream_t stream) {
    const float* x        = (const float*)d_in[0];
    const float* mem_keys = (const float*)d_in[1];
    const float* mem_vals = (const float*)d_in[2];
    const float* Wq       = (const float*)d_in[3];
    const float* bq       = (const float*)d_in[4];
    const float* Wk       = (const float*)d_in[5];
    const float* bk       = (const float*)d_in[6];
    const float* Wv       = (const float*)d_in[7];
    const float* bv       = (const float*)d_in[8];
    const float* gate     = (const float*)d_in[9];
    float* out = (float*)d_out;

    const size_t btd = (size_t)B_ * T_ * D_;   // 524288
    float* q    = (float*)d_ws;
    float* k    = q + btd;
    float* v    = k + btd;
    float* outc = v + btd;
    unsigned short* khi    = (unsigned short*)(outc + btd);   // 8 MB
    unsigned short* klo    = khi + (size_t)B_ * N_ * D_;      // 8 MB
    unsigned short* kcfrag = klo + (size_t)B_ * N_ * D_;      // 1 MB
    unsigned short* vfrag  = kcfrag + btd;                    // 1 MB
    unsigned short* whfrag = vfrag + btd;                     // 384 KB
    unsigned short* wlfrag = whfrag + (size_t)384 * 512;      // 384 KB

    wfrag_prep_kernel<<<96, 256, 0, stream>>>(Wq, Wk, Wv, whfrag, wlfrag);
    qkv_mfma_kernel<<<B_ * T_ / 32, 256, 0, stream>>>(x, whfrag, wlfrag,
                                                      bq, bk, bv, q, k, v);
    kfrag_prep_kernel<<<B_ * 512, 256, 0, stream>>>(mem_keys, khi, klo);
    causal_prep_kernel<<<B_ * 32, 256, 0, stream>>>(k, v, kcfrag, vfrag);
    causal_flash_kernel<<<B_ * 128, 256, 0, stream>>>(q, kcfrag, vfrag, outc);
    knn_mfma_kernel<<<512, 512, 0, stream>>>(q, khi, klo, mem_vals, outc, gate, out);
}

// Round 16
// 271.865 us; speedup vs baseline: 1.1615x; 1.1615x over previous
//
#include <hip/hip_runtime.h>
#include <math.h>

#define B_ 4
#define T_ 2048
#define C_ 1024
#define D_ 64
#define N_ 16384
#define K_ 32
#define SCALE 0.03125f   // 1/sqrt(1024)
#define NEGINF -3.402823e38f

typedef __attribute__((ext_vector_type(8))) short short8_t;  // 8 bf16 (4 VGPRs)
typedef __attribute__((ext_vector_type(4))) float f32x4;

__device__ __forceinline__ unsigned short f2bf(float x) {
    union { float f; unsigned u; } a; a.f = x;
    const unsigned r = a.u + 0x7fffu + ((a.u >> 16) & 1u);   // round-nearest-even
    return (unsigned short)(r >> 16);
}
__device__ __forceinline__ float bf2f(unsigned short h) {
    union { unsigned u; float f; } a; a.u = ((unsigned)h) << 16;
    return a.f;
}

// ---------------------------------------------------------------------------
// Pack [Wq|Wk|Wv] into bf16 hi/lo MFMA B-fragments (unchanged)
// ---------------------------------------------------------------------------
__global__ __launch_bounds__(256) void wfrag_prep_kernel(
    const float* __restrict__ Wq, const float* __restrict__ Wk,
    const float* __restrict__ Wv,
    unsigned short* __restrict__ whfrag, unsigned short* __restrict__ wlfrag)
{
    const int tid = threadIdx.x;
    const int w = tid >> 6, lane = tid & 63;
    const int id = blockIdx.x * 4 + w;          // 0..383
    const int ct = id >> 5, ks = id & 31;
    const float* W = (ct < 4) ? Wq : (ct < 8) ? Wk : Wv;
    const int colw = (ct & 3) * 16 + (lane & 15);
    const int k0 = ks * 32 + (lane >> 4) * 8;
    unsigned short* dh = whfrag + (size_t)id * 512 + (size_t)lane * 8;
    unsigned short* dl = wlfrag + (size_t)id * 512 + (size_t)lane * 8;
    #pragma unroll
    for (int j = 0; j < 8; ++j) {
        const float val = W[(size_t)(k0 + j) * D_ + colw];
        const unsigned short h = f2bf(val);
        dh[j] = h;
        dl[j] = f2bf(val - bf2f(h));
    }
}

// ---------------------------------------------------------------------------
// QKV projection via MFMA (unchanged from round 13)
// ---------------------------------------------------------------------------
__global__ __launch_bounds__(256) void qkv_mfma_kernel(
    const float* __restrict__ x,
    const unsigned short* __restrict__ whfrag, const unsigned short* __restrict__ wlfrag,
    const float* __restrict__ bq, const float* __restrict__ bk,
    const float* __restrict__ bv,
    float* __restrict__ q, float* __restrict__ k, float* __restrict__ v)
{
    __shared__ unsigned short xh[32][136], xl[32][136];
    const int tid = threadIdx.x;
    const int w = tid >> 6, lane = tid & 63;
    const int row0 = blockIdx.x * 32;
    const int rt = w & 1;
    const int ct0 = (w >> 1) * 6;

    f32x4 acc[6];
    #pragma unroll
    for (int i = 0; i < 6; ++i) {
        const int ct = ct0 + i;
        const float* bias = (ct < 4) ? bq : (ct < 8) ? bk : bv;
        const float bb = bias[(ct & 3) * 16 + (lane & 15)];
        acc[i] = (f32x4){bb, bb, bb, bb};
    }

    for (int kc = 0; kc < 8; ++kc) {
        __syncthreads();
        #pragma unroll
        for (int p = 0; p < 4; ++p) {
            const int fi = tid + p * 256;
            const int row = fi >> 5, c4 = fi & 31;
            const float4 xv =
                *(const float4*)(x + (size_t)(row0 + row) * C_ + kc * 128 + c4 * 4);
            const unsigned short h0 = f2bf(xv.x), h1 = f2bf(xv.y);
            const unsigned short h2 = f2bf(xv.z), h3 = f2bf(xv.w);
            xh[row][c4 * 4 + 0] = h0;  xl[row][c4 * 4 + 0] = f2bf(xv.x - bf2f(h0));
            xh[row][c4 * 4 + 1] = h1;  xl[row][c4 * 4 + 1] = f2bf(xv.y - bf2f(h1));
            xh[row][c4 * 4 + 2] = h2;  xl[row][c4 * 4 + 2] = f2bf(xv.z - bf2f(h2));
            xh[row][c4 * 4 + 3] = h3;  xl[row][c4 * 4 + 3] = f2bf(xv.w - bf2f(h3));
        }
        __syncthreads();
        #pragma unroll
        for (int ks = 0; ks < 4; ++ks) {
            const int aoff = ks * 32 + (lane >> 4) * 8;
            const short8_t ah = *(const short8_t*)&xh[rt * 16 + (lane & 15)][aoff];
            const short8_t al = *(const short8_t*)&xl[rt * 16 + (lane & 15)][aoff];
            #pragma unroll
            for (int i = 0; i < 6; ++i) {
                const size_t tb = ((size_t)(ct0 + i) * 32 + kc * 4 + ks) * 512
                                + (size_t)lane * 8;
                const short8_t wh = *(const short8_t*)(whfrag + tb);
                const short8_t wl = *(const short8_t*)(wlfrag + tb);
                acc[i] = __builtin_amdgcn_mfma_f32_16x16x32_bf16(ah, wh, acc[i], 0, 0, 0);
                acc[i] = __builtin_amdgcn_mfma_f32_16x16x32_bf16(ah, wl, acc[i], 0, 0, 0);
                acc[i] = __builtin_amdgcn_mfma_f32_16x16x32_bf16(al, wh, acc[i], 0, 0, 0);
            }
        }
    }

    #pragma unroll
    for (int i = 0; i < 6; ++i) {
        const int ct = ct0 + i;
        float* o = (ct < 4) ? q : (ct < 8) ? k : v;
        const int col = (ct & 3) * 16 + (lane & 15);
        const int rbase = row0 + rt * 16 + (lane >> 4) * 4;
        #pragma unroll
        for (int r = 0; r < 4; ++r)
            o[(size_t)(rbase + r) * D_ + col] = acc[i][r];
    }
}

// ---------------------------------------------------------------------------
// Pack mem_keys into bf16 hi/lo MFMA B-fragment layout (unchanged)
// ---------------------------------------------------------------------------
__global__ __launch_bounds__(256) void kfrag_prep_kernel(
    const float* __restrict__ keys, unsigned short* __restrict__ khi,
    unsigned short* __restrict__ klo)
{
    const int tid = threadIdx.x;
    const int lane = tid & 63;
    const int ks = (tid >> 6) & 1;
    const int b  = blockIdx.x >> 9;
    const int nt = ((blockIdx.x & 511) << 1) | (tid >> 7);
    const int key = nt * 16 + (lane & 15);
    const float* src = keys + ((size_t)b * N_ + key) * D_ + ks * 32 + (lane >> 4) * 8;
    const size_t o = (((size_t)b * 1024 + nt) * 2 + ks) * 512 + (size_t)lane * 8;
    #pragma unroll
    for (int j = 0; j < 8; ++j) {
        const float xv = src[j];
        const unsigned short h = f2bf(xv);
        khi[o + j] = h;
        klo[o + j] = f2bf(xv - bf2f(h));
    }
}

// ---------------------------------------------------------------------------
// Pack causal K and V into bf16 MFMA fragment buffers (unchanged)
// ---------------------------------------------------------------------------
__global__ __launch_bounds__(256) void causal_prep_kernel(
    const float* __restrict__ k, const float* __restrict__ v,
    unsigned short* __restrict__ kcfrag, unsigned short* __restrict__ vfrag)
{
    __shared__ float vtile[64][68];
    const int tid = threadIdx.x;
    const int b = blockIdx.x >> 5;
    const int n64 = blockIdx.x & 31;
    const int w = tid >> 6, lane = tid & 63;
    const int q16 = lane & 15, g = lane >> 4;

    const float4* in4 = (const float4*)(v + ((size_t)b * T_ + n64 * 64) * D_);
    #pragma unroll
    for (int p = 0; p < 4; ++p) {
        const int fi = tid + p * 256;
        const int row = fi >> 4, c4 = fi & 15;
        *(float4*)&vtile[row][c4 * 4] = in4[fi];
    }

    {
        const int key = (n64 * 4 + w) * 16 + q16;
        #pragma unroll
        for (int ks = 0; ks < 2; ++ks) {
            const float* src = k + ((size_t)b * T_ + key) * D_ + ks * 32 + g * 8;
            const float4 x0 = *(const float4*)(src);
            const float4 x1 = *(const float4*)(src + 4);
            unsigned short* dst = kcfrag
                + ((((size_t)b * 128 + n64 * 4 + w) * 2 + ks) * 512) + (size_t)lane * 8;
            dst[0] = f2bf(x0.x); dst[1] = f2bf(x0.y); dst[2] = f2bf(x0.z); dst[3] = f2bf(x0.w);
            dst[4] = f2bf(x1.x); dst[5] = f2bf(x1.y); dst[6] = f2bf(x1.z); dst[7] = f2bf(x1.w);
        }
    }
    __syncthreads();

    #pragma unroll
    for (int ks = 0; ks < 2; ++ks) {
        unsigned short* dst = vfrag
            + ((((size_t)b * 32 + n64) * 8 + ks * 4 + w) * 512) + (size_t)lane * 8;
        #pragma unroll
        for (int j = 0; j < 8; ++j)
            dst[j] = f2bf(vtile[ks * 32 + g * 8 + j][w * 16 + q16]);
    }
}

// ---------------------------------------------------------------------------
// Causal flash attention (round 7 + work-reversal kept from round 14)
// ---------------------------------------------------------------------------
__global__ __launch_bounds__(256) void causal_flash_kernel(
    const float* __restrict__ qg,
    const unsigned short* __restrict__ kcfrag, const unsigned short* __restrict__ vfrag,
    float* __restrict__ outc)
{
    __shared__ unsigned int plds[64][36];
    __shared__ float po[4][64][17];
    __shared__ float pml[4][2][16];
    const int tid = threadIdx.x;
    const int w = tid >> 6, lane = tid & 63;
    const int q16 = lane & 15, g = lane >> 4;
    const int b = blockIdx.x >> 7;
    const int qt = 127 - (blockIdx.x & 127);   // big-work blocks dispatch first
    const int t0 = qt * 16;
    const int qglob = t0 + q16;
    const int n64 = (qt >> 2) + 1;

    short8_t qf[2];
    #pragma unroll
    for (int ks = 0; ks < 2; ++ks) {
        const float* src = qg + ((size_t)b * T_ + qglob) * D_ + ks * 32 + g * 8;
        const float4 x0 = *(const float4*)(src);
        const float4 x1 = *(const float4*)(src + 4);
        qf[ks][0] = (short)f2bf(x0.x); qf[ks][1] = (short)f2bf(x0.y);
        qf[ks][2] = (short)f2bf(x0.z); qf[ks][3] = (short)f2bf(x0.w);
        qf[ks][4] = (short)f2bf(x1.x); qf[ks][5] = (short)f2bf(x1.y);
        qf[ks][6] = (short)f2bf(x1.z); qf[ks][7] = (short)f2bf(x1.w);
    }

    float m = -1.0e30f, l = 0.f;
    f32x4 o[4];
    #pragma unroll
    for (int dt = 0; dt < 4; ++dt) o[dt] = (f32x4){0.f, 0.f, 0.f, 0.f};

    const int qrow = w * 16 + q16;

    for (int n = w; n < n64; n += 4) {
        short8_t kf[4][2];
        #pragma unroll
        for (int a = 0; a < 4; ++a)
            #pragma unroll
            for (int ks = 0; ks < 2; ++ks)
                kf[a][ks] = *(const short8_t*)(kcfrag
                    + ((((size_t)b * 128 + n * 4 + a) * 2 + ks) * 512) + (size_t)lane * 8);
        f32x4 st[4];
        #pragma unroll
        for (int a = 0; a < 4; ++a) {
            st[a] = (f32x4){0.f, 0.f, 0.f, 0.f};
            st[a] = __builtin_amdgcn_mfma_f32_16x16x32_bf16(kf[a][0], qf[0], st[a], 0, 0, 0);
            st[a] = __builtin_amdgcn_mfma_f32_16x16x32_bf16(kf[a][1], qf[1], st[a], 0, 0, 0);
        }

        float sv[4][4];
        float pm = -1.0e30f;
        #pragma unroll
        for (int a = 0; a < 4; ++a)
            #pragma unroll
            for (int r = 0; r < 4; ++r) {
                const int kk = n * 64 + a * 16 + g * 4 + r;
                float x = st[a][r] * SCALE;
                x = (kk <= qglob) ? x : -1.0e31f;
                sv[a][r] = x;
                pm = fmaxf(pm, x);
            }
        pm = fmaxf(pm, __shfl_xor(pm, 16));
        pm = fmaxf(pm, __shfl_xor(pm, 32));
        const float mn = fmaxf(m, pm);
        const float al = __expf(m - mn);
        float rs = 0.f;
        float ev[4][4];
        #pragma unroll
        for (int a = 0; a < 4; ++a)
            #pragma unroll
            for (int r = 0; r < 4; ++r) {
                const float e = __expf(sv[a][r] - mn);
                ev[a][r] = e;
                rs += e;
            }
        rs += __shfl_xor(rs, 16);
        rs += __shfl_xor(rs, 32);
        l = l * al + rs;
        m = mn;
        #pragma unroll
        for (int dt = 0; dt < 4; ++dt) o[dt] *= al;

        #pragma unroll
        for (int a = 0; a < 4; ++a)
            #pragma unroll
            for (int rp = 0; rp < 2; ++rp)
                plds[qrow][a * 8 + g * 2 + rp] =
                    (unsigned)f2bf(ev[a][2 * rp]) | ((unsigned)f2bf(ev[a][2 * rp + 1]) << 16);
        #pragma unroll
        for (int ks = 0; ks < 2; ++ks) {
            const short8_t pf = *(const short8_t*)&plds[qrow][ks * 16 + g * 4];
            #pragma unroll
            for (int dt = 0; dt < 4; ++dt) {
                const short8_t vf = *(const short8_t*)(vfrag
                    + ((((size_t)b * 32 + n) * 8 + ks * 4 + dt) * 512) + (size_t)lane * 8);
                o[dt] = __builtin_amdgcn_mfma_f32_16x16x32_bf16(vf, pf, o[dt], 0, 0, 0);
            }
        }
    }

    #pragma unroll
    for (int dt = 0; dt < 4; ++dt)
        #pragma unroll
        for (int r = 0; r < 4; ++r)
            po[w][dt * 16 + g * 4 + r][q16] = o[dt][r];
    if (g == 0) { pml[w][0][q16] = m; pml[w][1][q16] = l; }
    __syncthreads();

    {
        const int q = tid & 15;
        const int dgrp = tid >> 4;
        float mw[4], lw[4];
        #pragma unroll
        for (int ww = 0; ww < 4; ++ww) { mw[ww] = pml[ww][0][q]; lw[ww] = pml[ww][1][q]; }
        const float M = fmaxf(fmaxf(mw[0], mw[1]), fmaxf(mw[2], mw[3]));
        float wgt[4], L = 0.f;
        #pragma unroll
        for (int ww = 0; ww < 4; ++ww) {
            wgt[ww] = __expf(mw[ww] - M);
            L += lw[ww] * wgt[ww];
        }
        const float inv = 1.0f / L;
        float4 res;
        float* rp = &res.x;
        #pragma unroll
        for (int i = 0; i < 4; ++i) {
            const int d = dgrp * 4 + i;
            float s = 0.f;
            #pragma unroll
            for (int ww = 0; ww < 4; ++ww) s += po[ww][d][q] * wgt[ww];
            rp[i] = s * inv;
        }
        *(float4*)(outc + ((size_t)b * T_ + t0 + q) * D_ + dgrp * 4) = res;
    }
}

// ---------------------------------------------------------------------------
// kNN (round-13/round-11 proven 200us): TQ=16, 512 threads (8 waves),
// grid 512, double-buffered [2][16][260] score LDS (stride 260 % 32 = 4 ->
// conflict-free), static-j candidate stream, per-chunk t32, fused epilogue.
// ---------------------------------------------------------------------------
__global__ __launch_bounds__(512) void knn_mfma_kernel(
    const float* __restrict__ qg,
    const unsigned short* __restrict__ khi, const unsigned short* __restrict__ klo,
    const float* __restrict__ mem_vals, const float* __restrict__ outc,
    const float* __restrict__ gate, float* __restrict__ outp)
{
    __shared__ float sc_lds[2][16][260];   // ~33 KB
    const int tid = threadIdx.x;
    const int w = tid >> 6, lane = tid & 63;     // 8 waves
    const int bid = blockIdx.x;                  // 512 blocks
    const int b  = (bid & 7) >> 1;               // batch -> XCD pair
    const int qt = ((bid >> 3) << 1) | (bid & 1); // 0..127
    const int t0 = qt * 16;

    short8_t qh[2], ql[2];
    {
        const int qrow = t0 + (lane & 15);
        const float* qs = qg + ((size_t)b * T_ + qrow) * D_ + (lane >> 4) * 8;
        #pragma unroll
        for (int ks2 = 0; ks2 < 2; ++ks2) {
            #pragma unroll
            for (int j = 0; j < 8; ++j) {
                const float xv = qs[ks2 * 32 + j];
                const unsigned short h = f2bf(xv);
                qh[ks2][j] = (short)h;
                ql[ks2][j] = (short)f2bf(xv - bf2f(h));
            }
        }
    }

    const int qrow4 = (lane >> 4) * 4;
    const int c16 = lane & 15;

#define LOADFRAGS(CC, KH, KL)                                                  \
    {                                                                          \
        _Pragma("unroll")                                                      \
        for (int tt = 0; tt < 2; ++tt) {                                       \
            const int tl = w + 8 * tt;                                         \
            const size_t kb = (((size_t)b * 1024 + (size_t)(CC) * 16 + tl) * 2) * 512 \
                            + (size_t)lane * 8;                                \
            KH[tt][0] = *(const short8_t*)(khi + kb);                          \
            KH[tt][1] = *(const short8_t*)(khi + kb + 512);                    \
            KL[tt][0] = *(const short8_t*)(klo + kb);                          \
            KL[tt][1] = *(const short8_t*)(klo + kb + 512);                    \
        }                                                                      \
    }

#define MFMAWRITE(BUF, KH, KL)                                                 \
    {                                                                          \
        _Pragma("unroll")                                                      \
        for (int tt = 0; tt < 2; ++tt) {                                       \
            const int tl = w + 8 * tt;                                         \
            f32x4 acc = {0.f, 0.f, 0.f, 0.f};                                  \
            acc = __builtin_amdgcn_mfma_f32_16x16x32_bf16(qh[0], KH[tt][0], acc, 0, 0, 0); \
            acc = __builtin_amdgcn_mfma_f32_16x16x32_bf16(qh[1], KH[tt][1], acc, 0, 0, 0); \
            acc = __builtin_amdgcn_mfma_f32_16x16x32_bf16(qh[0], KL[tt][0], acc, 0, 0, 0); \
            acc = __builtin_amdgcn_mfma_f32_16x16x32_bf16(qh[1], KL[tt][1], acc, 0, 0, 0); \
            acc = __builtin_amdgcn_mfma_f32_16x16x32_bf16(ql[0], KH[tt][0], acc, 0, 0, 0); \
            acc = __builtin_amdgcn_mfma_f32_16x16x32_bf16(ql[1], KH[tt][1], acc, 0, 0, 0); \
            const int col = tl * 16 + c16;                                     \
            _Pragma("unroll")                                                  \
            for (int r = 0; r < 4; ++r) sc_lds[BUF][qrow4 + r][col] = acc[r];  \
        }                                                                      \
    }

    float rv[2];  int rid_[2];  float t32[2];
    #pragma unroll
    for (int qq = 0; qq < 2; ++qq) {
        rv[qq] = NEGINF; rid_[qq] = 0x7fffffff; t32[qq] = NEGINF;
    }

    {
        short8_t kh[2][2], kl[2][2];
        LOADFRAGS(0, kh, kl);
        MFMAWRITE(0, kh, kl);
    }
    __syncthreads();

    for (int c = 0; c < 64; ++c) {
        short8_t kh[2][2], kl[2][2];
        if (c < 63) LOADFRAGS(c + 1, kh, kl);

        float s4[2][4];
        #pragma unroll
        for (int qq = 0; qq < 2; ++qq)
            *(float4*)(&s4[qq][0]) = *(const float4*)&sc_lds[c & 1][w * 2 + qq][lane * 4];

        if (c == 0) {
            #pragma unroll
            for (int qq = 0; qq < 2; ++qq) {
                float lmax = NEGINF; int lslot = 0;
                #pragma unroll
                for (int j = 0; j < 4; ++j)
                    if (s4[qq][j] > lmax) { lmax = s4[qq][j]; lslot = j; }
                for (int it = 0; it < 32; ++it) {
                    float wm = lmax;
                    #pragma unroll
                    for (int off = 32; off; off >>= 1)
                        wm = fmaxf(wm, __shfl_xor(wm, off));
                    const unsigned long long bal = __ballot(lmax == wm);
                    const int winner = __ffsll((unsigned long long)bal) - 1;
                    const int wslot  = __shfl(lslot, winner);
                    const int widx   = (winner << 2) + (wslot & 3);
                    const unsigned long long gb = __ballot((lane < K_) && (rv[qq] > wm));
                    const int pos = __popcll(gb);
                    const float sv = __shfl_up(rv[qq], 1);
                    const int   si = __shfl_up(rid_[qq], 1);
                    if (lane > pos)       { rv[qq] = sv; rid_[qq] = si; }
                    else if (lane == pos) { rv[qq] = wm; rid_[qq] = widx; }
                    if (lane == winner) {
                        float nm = NEGINF; int ns = 0;
                        #pragma unroll
                        for (int j = 0; j < 4; ++j) {
                            const float vj = (j == lslot) ? NEGINF : s4[qq][j];
                            s4[qq][j] = vj;
                            if (vj > nm) { nm = vj; ns = j; }
                        }
                        lmax = nm; lslot = ns;
                    }
                }
                t32[qq] = __shfl(rv[qq], 31);
            }
        } else {
            #pragma unroll
            for (int qq = 0; qq < 2; ++qq) {
                #pragma unroll
                for (int j = 0; j < 4; ++j) {
                    unsigned long long bb = __ballot(s4[qq][j] > t32[qq]);
                    while (bb) {
                        const int L = __ffsll(bb) - 1;
                        bb &= bb - 1;
                        const float xv = __shfl(s4[qq][j], L);
                        const int xi = (c << 8) + (L << 2) + j;
                        const unsigned long long gb =
                            __ballot((lane < K_) && (rv[qq] > xv));
                        const int pos = __popcll(gb);
                        const float sv = __shfl_up(rv[qq], 1);
                        const int   si = __shfl_up(rid_[qq], 1);
                        if (lane > pos)       { rv[qq] = sv; rid_[qq] = si; }
                        else if (lane == pos) { rv[qq] = xv; rid_[qq] = xi; }
                    }
                }
                t32[qq] = __shfl(rv[qq], 31);   // once per chunk
            }
        }

        if (c < 63) MFMAWRITE((c + 1) & 1, kh, kl);
        __syncthreads();
    }

#undef LOADFRAGS
#undef MFMAWRITE

    const float gv = gate[0];
    const float* vb = mem_vals + (size_t)b * N_ * D_;
    #pragma unroll
    for (int qq = 0; qq < 2; ++qq) {
        const float m = __shfl(rv[qq], 0);
        float wgt = (lane < K_) ? __expf((rv[qq] - m) * SCALE) : 0.f;
        float ssum = wgt;
        #pragma unroll
        for (int off = 32; off; off >>= 1) ssum += __shfl_xor(ssum, off);
        float acc = 0.f;
        for (int i = 0; i < K_; ++i) {
            const float wi = __shfl(wgt, i);
            const int   ii = __shfl(rid_[qq], i);
            acc += wi * vb[(size_t)ii * D_ + lane];
        }
        const size_t o = ((size_t)(b * T_ + t0 + w * 2 + qq)) * D_ + lane;
        outp[o] = outc[o] * gv + (acc / ssum) * (1.f - gv);
    }
}

extern "C" void kernel_launch(void* const* d_in, const int* in_sizes, int n_in,
                              void* d_out, int out_size, void* d_ws, size_t ws_size,
                              hipStream_t stream) {
    const float* x        = (const float*)d_in[0];
    const float* mem_keys = (const float*)d_in[1];
    const float* mem_vals = (const float*)d_in[2];
    const float* Wq       = (const float*)d_in[3];
    const float* bq       = (const float*)d_in[4];
    const float* Wk       = (const float*)d_in[5];
    const float* bk       = (const float*)d_in[6];
    const float* Wv       = (const float*)d_in[7];
    const float* bv       = (const float*)d_in[8];
    const float* gate     = (const float*)d_in[9];
    float* out = (float*)d_out;

    const size_t btd = (size_t)B_ * T_ * D_;   // 524288
    float* q    = (float*)d_ws;
    float* k    = q + btd;
    float* v    = k + btd;
    float* outc = v + btd;
    unsigned short* khi    = (unsigned short*)(outc + btd);   // 8 MB
    unsigned short* klo    = khi + (size_t)B_ * N_ * D_;      // 8 MB
    unsigned short* kcfrag = klo + (size_t)B_ * N_ * D_;      // 1 MB
    unsigned short* vfrag  = kcfrag + btd;                    // 1 MB
    unsigned short* whfrag = vfrag + btd;                     // 384 KB
    unsigned short* wlfrag = whfrag + (size_t)384 * 512;      // 384 KB

    wfrag_prep_kernel<<<96, 256, 0, stream>>>(Wq, Wk, Wv, whfrag, wlfrag);
    qkv_mfma_kernel<<<B_ * T_ / 32, 256, 0, stream>>>(x, whfrag, wlfrag,
                                                      bq, bk, bv, q, k, v);
    kfrag_prep_kernel<<<B_ * 512, 256, 0, stream>>>(mem_keys, khi, klo);
    causal_prep_kernel<<<B_ * 32, 256, 0, stream>>>(k, v, kcfrag, vfrag);
    causal_flash_kernel<<<B_ * 128, 256, 0, stream>>>(q, kcfrag, vfrag, outc);
    knn_mfma_kernel<<<512, 512, 0, stream>>>(q, khi, klo, mem_vals, outc, gate, out);
}

// Round 17
// 265.810 us; speedup vs baseline: 1.1879x; 1.0228x over previous
//
#include <hip/hip_runtime.h>
#include <math.h>

#define B_ 4
#define T_ 2048
#define C_ 1024
#define D_ 64
#define N_ 16384
#define K_ 32
#define SCALE 0.03125f   // 1/sqrt(1024)
#define NEGINF -3.402823e38f

typedef __attribute__((ext_vector_type(8))) short short8_t;  // 8 bf16 (4 VGPRs)
typedef __attribute__((ext_vector_type(4))) float f32x4;

__device__ __forceinline__ unsigned short f2bf(float x) {
    union { float f; unsigned u; } a; a.f = x;
    const unsigned r = a.u + 0x7fffu + ((a.u >> 16) & 1u);   // round-nearest-even
    return (unsigned short)(r >> 16);
}
__device__ __forceinline__ float bf2f(unsigned short h) {
    union { unsigned u; float f; } a; a.u = ((unsigned)h) << 16;
    return a.f;
}

// ---------------------------------------------------------------------------
// Pack [Wq|Wk|Wv] into bf16 hi/lo MFMA B-fragments (unchanged)
// ---------------------------------------------------------------------------
__global__ __launch_bounds__(256) void wfrag_prep_kernel(
    const float* __restrict__ Wq, const float* __restrict__ Wk,
    const float* __restrict__ Wv,
    unsigned short* __restrict__ whfrag, unsigned short* __restrict__ wlfrag)
{
    const int tid = threadIdx.x;
    const int w = tid >> 6, lane = tid & 63;
    const int id = blockIdx.x * 4 + w;          // 0..383
    const int ct = id >> 5, ks = id & 31;
    const float* W = (ct < 4) ? Wq : (ct < 8) ? Wk : Wv;
    const int colw = (ct & 3) * 16 + (lane & 15);
    const int k0 = ks * 32 + (lane >> 4) * 8;
    unsigned short* dh = whfrag + (size_t)id * 512 + (size_t)lane * 8;
    unsigned short* dl = wlfrag + (size_t)id * 512 + (size_t)lane * 8;
    #pragma unroll
    for (int j = 0; j < 8; ++j) {
        const float val = W[(size_t)(k0 + j) * D_ + colw];
        const unsigned short h = f2bf(val);
        dh[j] = h;
        dl[j] = f2bf(val - bf2f(h));
    }
}

// ---------------------------------------------------------------------------
// QKV projection via MFMA (unchanged from round 13)
// ---------------------------------------------------------------------------
__global__ __launch_bounds__(256) void qkv_mfma_kernel(
    const float* __restrict__ x,
    const unsigned short* __restrict__ whfrag, const unsigned short* __restrict__ wlfrag,
    const float* __restrict__ bq, const float* __restrict__ bk,
    const float* __restrict__ bv,
    float* __restrict__ q, float* __restrict__ k, float* __restrict__ v)
{
    __shared__ unsigned short xh[32][136], xl[32][136];
    const int tid = threadIdx.x;
    const int w = tid >> 6, lane = tid & 63;
    const int row0 = blockIdx.x * 32;
    const int rt = w & 1;
    const int ct0 = (w >> 1) * 6;

    f32x4 acc[6];
    #pragma unroll
    for (int i = 0; i < 6; ++i) {
        const int ct = ct0 + i;
        const float* bias = (ct < 4) ? bq : (ct < 8) ? bk : bv;
        const float bb = bias[(ct & 3) * 16 + (lane & 15)];
        acc[i] = (f32x4){bb, bb, bb, bb};
    }

    for (int kc = 0; kc < 8; ++kc) {
        __syncthreads();
        #pragma unroll
        for (int p = 0; p < 4; ++p) {
            const int fi = tid + p * 256;
            const int row = fi >> 5, c4 = fi & 31;
            const float4 xv =
                *(const float4*)(x + (size_t)(row0 + row) * C_ + kc * 128 + c4 * 4);
            const unsigned short h0 = f2bf(xv.x), h1 = f2bf(xv.y);
            const unsigned short h2 = f2bf(xv.z), h3 = f2bf(xv.w);
            xh[row][c4 * 4 + 0] = h0;  xl[row][c4 * 4 + 0] = f2bf(xv.x - bf2f(h0));
            xh[row][c4 * 4 + 1] = h1;  xl[row][c4 * 4 + 1] = f2bf(xv.y - bf2f(h1));
            xh[row][c4 * 4 + 2] = h2;  xl[row][c4 * 4 + 2] = f2bf(xv.z - bf2f(h2));
            xh[row][c4 * 4 + 3] = h3;  xl[row][c4 * 4 + 3] = f2bf(xv.w - bf2f(h3));
        }
        __syncthreads();
        #pragma unroll
        for (int ks = 0; ks < 4; ++ks) {
            const int aoff = ks * 32 + (lane >> 4) * 8;
            const short8_t ah = *(const short8_t*)&xh[rt * 16 + (lane & 15)][aoff];
            const short8_t al = *(const short8_t*)&xl[rt * 16 + (lane & 15)][aoff];
            #pragma unroll
            for (int i = 0; i < 6; ++i) {
                const size_t tb = ((size_t)(ct0 + i) * 32 + kc * 4 + ks) * 512
                                + (size_t)lane * 8;
                const short8_t wh = *(const short8_t*)(whfrag + tb);
                const short8_t wl = *(const short8_t*)(wlfrag + tb);
                acc[i] = __builtin_amdgcn_mfma_f32_16x16x32_bf16(ah, wh, acc[i], 0, 0, 0);
                acc[i] = __builtin_amdgcn_mfma_f32_16x16x32_bf16(ah, wl, acc[i], 0, 0, 0);
                acc[i] = __builtin_amdgcn_mfma_f32_16x16x32_bf16(al, wh, acc[i], 0, 0, 0);
            }
        }
    }

    #pragma unroll
    for (int i = 0; i < 6; ++i) {
        const int ct = ct0 + i;
        float* o = (ct < 4) ? q : (ct < 8) ? k : v;
        const int col = (ct & 3) * 16 + (lane & 15);
        const int rbase = row0 + rt * 16 + (lane >> 4) * 4;
        #pragma unroll
        for (int r = 0; r < 4; ++r)
            o[(size_t)(rbase + r) * D_ + col] = acc[i][r];
    }
}

// ---------------------------------------------------------------------------
// Pack mem_keys into bf16 hi/lo MFMA B-fragment layout (unchanged)
// ---------------------------------------------------------------------------
__global__ __launch_bounds__(256) void kfrag_prep_kernel(
    const float* __restrict__ keys, unsigned short* __restrict__ khi,
    unsigned short* __restrict__ klo)
{
    const int tid = threadIdx.x;
    const int lane = tid & 63;
    const int ks = (tid >> 6) & 1;
    const int b  = blockIdx.x >> 9;
    const int nt = ((blockIdx.x & 511) << 1) | (tid >> 7);
    const int key = nt * 16 + (lane & 15);
    const float* src = keys + ((size_t)b * N_ + key) * D_ + ks * 32 + (lane >> 4) * 8;
    const size_t o = (((size_t)b * 1024 + nt) * 2 + ks) * 512 + (size_t)lane * 8;
    #pragma unroll
    for (int j = 0; j < 8; ++j) {
        const float xv = src[j];
        const unsigned short h = f2bf(xv);
        khi[o + j] = h;
        klo[o + j] = f2bf(xv - bf2f(h));
    }
}

// ---------------------------------------------------------------------------
// Pack causal K and V into bf16 MFMA fragment buffers (unchanged)
// ---------------------------------------------------------------------------
__global__ __launch_bounds__(256) void causal_prep_kernel(
    const float* __restrict__ k, const float* __restrict__ v,
    unsigned short* __restrict__ kcfrag, unsigned short* __restrict__ vfrag)
{
    __shared__ float vtile[64][68];
    const int tid = threadIdx.x;
    const int b = blockIdx.x >> 5;
    const int n64 = blockIdx.x & 31;
    const int w = tid >> 6, lane = tid & 63;
    const int q16 = lane & 15, g = lane >> 4;

    const float4* in4 = (const float4*)(v + ((size_t)b * T_ + n64 * 64) * D_);
    #pragma unroll
    for (int p = 0; p < 4; ++p) {
        const int fi = tid + p * 256;
        const int row = fi >> 4, c4 = fi & 15;
        *(float4*)&vtile[row][c4 * 4] = in4[fi];
    }

    {
        const int key = (n64 * 4 + w) * 16 + q16;
        #pragma unroll
        for (int ks = 0; ks < 2; ++ks) {
            const float* src = k + ((size_t)b * T_ + key) * D_ + ks * 32 + g * 8;
            const float4 x0 = *(const float4*)(src);
            const float4 x1 = *(const float4*)(src + 4);
            unsigned short* dst = kcfrag
                + ((((size_t)b * 128 + n64 * 4 + w) * 2 + ks) * 512) + (size_t)lane * 8;
            dst[0] = f2bf(x0.x); dst[1] = f2bf(x0.y); dst[2] = f2bf(x0.z); dst[3] = f2bf(x0.w);
            dst[4] = f2bf(x1.x); dst[5] = f2bf(x1.y); dst[6] = f2bf(x1.z); dst[7] = f2bf(x1.w);
        }
    }
    __syncthreads();

    #pragma unroll
    for (int ks = 0; ks < 2; ++ks) {
        unsigned short* dst = vfrag
            + ((((size_t)b * 32 + n64) * 8 + ks * 4 + w) * 512) + (size_t)lane * 8;
        #pragma unroll
        for (int j = 0; j < 8; ++j)
            dst[j] = f2bf(vtile[ks * 32 + g * 8 + j][w * 16 + q16]);
    }
}

// ---------------------------------------------------------------------------
// Causal flash attention (unchanged: round 7 + work-reversal)
// ---------------------------------------------------------------------------
__global__ __launch_bounds__(256) void causal_flash_kernel(
    const float* __restrict__ qg,
    const unsigned short* __restrict__ kcfrag, const unsigned short* __restrict__ vfrag,
    float* __restrict__ outc)
{
    __shared__ unsigned int plds[64][36];
    __shared__ float po[4][64][17];
    __shared__ float pml[4][2][16];
    const int tid = threadIdx.x;
    const int w = tid >> 6, lane = tid & 63;
    const int q16 = lane & 15, g = lane >> 4;
    const int b = blockIdx.x >> 7;
    const int qt = 127 - (blockIdx.x & 127);   // big-work blocks dispatch first
    const int t0 = qt * 16;
    const int qglob = t0 + q16;
    const int n64 = (qt >> 2) + 1;

    short8_t qf[2];
    #pragma unroll
    for (int ks = 0; ks < 2; ++ks) {
        const float* src = qg + ((size_t)b * T_ + qglob) * D_ + ks * 32 + g * 8;
        const float4 x0 = *(const float4*)(src);
        const float4 x1 = *(const float4*)(src + 4);
        qf[ks][0] = (short)f2bf(x0.x); qf[ks][1] = (short)f2bf(x0.y);
        qf[ks][2] = (short)f2bf(x0.z); qf[ks][3] = (short)f2bf(x0.w);
        qf[ks][4] = (short)f2bf(x1.x); qf[ks][5] = (short)f2bf(x1.y);
        qf[ks][6] = (short)f2bf(x1.z); qf[ks][7] = (short)f2bf(x1.w);
    }

    float m = -1.0e30f, l = 0.f;
    f32x4 o[4];
    #pragma unroll
    for (int dt = 0; dt < 4; ++dt) o[dt] = (f32x4){0.f, 0.f, 0.f, 0.f};

    const int qrow = w * 16 + q16;

    for (int n = w; n < n64; n += 4) {
        short8_t kf[4][2];
        #pragma unroll
        for (int a = 0; a < 4; ++a)
            #pragma unroll
            for (int ks = 0; ks < 2; ++ks)
                kf[a][ks] = *(const short8_t*)(kcfrag
                    + ((((size_t)b * 128 + n * 4 + a) * 2 + ks) * 512) + (size_t)lane * 8);
        f32x4 st[4];
        #pragma unroll
        for (int a = 0; a < 4; ++a) {
            st[a] = (f32x4){0.f, 0.f, 0.f, 0.f};
            st[a] = __builtin_amdgcn_mfma_f32_16x16x32_bf16(kf[a][0], qf[0], st[a], 0, 0, 0);
            st[a] = __builtin_amdgcn_mfma_f32_16x16x32_bf16(kf[a][1], qf[1], st[a], 0, 0, 0);
        }

        float sv[4][4];
        float pm = -1.0e30f;
        #pragma unroll
        for (int a = 0; a < 4; ++a)
            #pragma unroll
            for (int r = 0; r < 4; ++r) {
                const int kk = n * 64 + a * 16 + g * 4 + r;
                float x = st[a][r] * SCALE;
                x = (kk <= qglob) ? x : -1.0e31f;
                sv[a][r] = x;
                pm = fmaxf(pm, x);
            }
        pm = fmaxf(pm, __shfl_xor(pm, 16));
        pm = fmaxf(pm, __shfl_xor(pm, 32));
        const float mn = fmaxf(m, pm);
        const float al = __expf(m - mn);
        float rs = 0.f;
        float ev[4][4];
        #pragma unroll
        for (int a = 0; a < 4; ++a)
            #pragma unroll
            for (int r = 0; r < 4; ++r) {
                const float e = __expf(sv[a][r] - mn);
                ev[a][r] = e;
                rs += e;
            }
        rs += __shfl_xor(rs, 16);
        rs += __shfl_xor(rs, 32);
        l = l * al + rs;
        m = mn;
        #pragma unroll
        for (int dt = 0; dt < 4; ++dt) o[dt] *= al;

        #pragma unroll
        for (int a = 0; a < 4; ++a)
            #pragma unroll
            for (int rp = 0; rp < 2; ++rp)
                plds[qrow][a * 8 + g * 2 + rp] =
                    (unsigned)f2bf(ev[a][2 * rp]) | ((unsigned)f2bf(ev[a][2 * rp + 1]) << 16);
        #pragma unroll
        for (int ks = 0; ks < 2; ++ks) {
            const short8_t pf = *(const short8_t*)&plds[qrow][ks * 16 + g * 4];
            #pragma unroll
            for (int dt = 0; dt < 4; ++dt) {
                const short8_t vf = *(const short8_t*)(vfrag
                    + ((((size_t)b * 32 + n) * 8 + ks * 4 + dt) * 512) + (size_t)lane * 8);
                o[dt] = __builtin_amdgcn_mfma_f32_16x16x32_bf16(vf, pf, o[dt], 0, 0, 0);
            }
        }
    }

    #pragma unroll
    for (int dt = 0; dt < 4; ++dt)
        #pragma unroll
        for (int r = 0; r < 4; ++r)
            po[w][dt * 16 + g * 4 + r][q16] = o[dt][r];
    if (g == 0) { pml[w][0][q16] = m; pml[w][1][q16] = l; }
    __syncthreads();

    {
        const int q = tid & 15;
        const int dgrp = tid >> 4;
        float mw[4], lw[4];
        #pragma unroll
        for (int ww = 0; ww < 4; ++ww) { mw[ww] = pml[ww][0][q]; lw[ww] = pml[ww][1][q]; }
        const float M = fmaxf(fmaxf(mw[0], mw[1]), fmaxf(mw[2], mw[3]));
        float wgt[4], L = 0.f;
        #pragma unroll
        for (int ww = 0; ww < 4; ++ww) {
            wgt[ww] = __expf(mw[ww] - M);
            L += lw[ww] * wgt[ww];
        }
        const float inv = 1.0f / L;
        float4 res;
        float* rp = &res.x;
        #pragma unroll
        for (int i = 0; i < 4; ++i) {
            const int d = dgrp * 4 + i;
            float s = 0.f;
            #pragma unroll
            for (int ww = 0; ww < 4; ++ww) s += po[ww][d][q] * wgt[ww];
            rp[i] = s * inv;
        }
        *(float4*)(outc + ((size_t)b * T_ + t0 + q) * D_ + dgrp * 4) = res;
    }
}

// ---------------------------------------------------------------------------
// kNN v13: round-11 structure + DEPTH-2 fragment prefetch.  Loop unrolled by
// 2 with named register sets A/B (no runtime-indexed frag arrays).  At
// iteration c: issue loads for c+2, select chunk c, MFMA chunk c+1 from
// fragments issued a full chunk (~3us) earlier -> load latency fully off the
// convoy path.  Everything else verbatim from the proven 200us kernel.
// ---------------------------------------------------------------------------
__global__ __launch_bounds__(512) void knn_mfma_kernel(
    const float* __restrict__ qg,
    const unsigned short* __restrict__ khi, const unsigned short* __restrict__ klo,
    const float* __restrict__ mem_vals, const float* __restrict__ outc,
    const float* __restrict__ gate, float* __restrict__ outp)
{
    __shared__ float sc_lds[2][16][260];   // ~33 KB
    const int tid = threadIdx.x;
    const int w = tid >> 6, lane = tid & 63;     // 8 waves
    const int bid = blockIdx.x;                  // 512 blocks
    const int b  = (bid & 7) >> 1;               // batch -> XCD pair
    const int qt = ((bid >> 3) << 1) | (bid & 1); // 0..127
    const int t0 = qt * 16;

    short8_t qh[2], ql[2];
    {
        const int qrow = t0 + (lane & 15);
        const float* qs = qg + ((size_t)b * T_ + qrow) * D_ + (lane >> 4) * 8;
        #pragma unroll
        for (int ks2 = 0; ks2 < 2; ++ks2) {
            #pragma unroll
            for (int j = 0; j < 8; ++j) {
                const float xv = qs[ks2 * 32 + j];
                const unsigned short h = f2bf(xv);
                qh[ks2][j] = (short)h;
                ql[ks2][j] = (short)f2bf(xv - bf2f(h));
            }
        }
    }

    const int qrow4 = (lane >> 4) * 4;
    const int c16 = lane & 15;

#define LOADFRAGS(CC, KH, KL)                                                  \
    {                                                                          \
        _Pragma("unroll")                                                      \
        for (int tt = 0; tt < 2; ++tt) {                                       \
            const int tl = w + 8 * tt;                                         \
            const size_t kb = (((size_t)b * 1024 + (size_t)(CC) * 16 + tl) * 2) * 512 \
                            + (size_t)lane * 8;                                \
            KH[tt][0] = *(const short8_t*)(khi + kb);                          \
            KH[tt][1] = *(const short8_t*)(khi + kb + 512);                    \
            KL[tt][0] = *(const short8_t*)(klo + kb);                          \
            KL[tt][1] = *(const short8_t*)(klo + kb + 512);                    \
        }                                                                      \
    }

#define MFMAWRITE(BUF, KH, KL)                                                 \
    {                                                                          \
        _Pragma("unroll")                                                      \
        for (int tt = 0; tt < 2; ++tt) {                                       \
            const int tl = w + 8 * tt;                                         \
            f32x4 acc = {0.f, 0.f, 0.f, 0.f};                                  \
            acc = __builtin_amdgcn_mfma_f32_16x16x32_bf16(qh[0], KH[tt][0], acc, 0, 0, 0); \
            acc = __builtin_amdgcn_mfma_f32_16x16x32_bf16(qh[1], KH[tt][1], acc, 0, 0, 0); \
            acc = __builtin_amdgcn_mfma_f32_16x16x32_bf16(qh[0], KL[tt][0], acc, 0, 0, 0); \
            acc = __builtin_amdgcn_mfma_f32_16x16x32_bf16(qh[1], KL[tt][1], acc, 0, 0, 0); \
            acc = __builtin_amdgcn_mfma_f32_16x16x32_bf16(ql[0], KH[tt][0], acc, 0, 0, 0); \
            acc = __builtin_amdgcn_mfma_f32_16x16x32_bf16(ql[1], KH[tt][1], acc, 0, 0, 0); \
            const int col = tl * 16 + c16;                                     \
            _Pragma("unroll")                                                  \
            for (int r = 0; r < 4; ++r) sc_lds[BUF][qrow4 + r][col] = acc[r];  \
        }                                                                      \
    }

// selection for chunk CC out of buffer CC&1 (warmup at CC==0)
#define SELECT(CC)                                                             \
    {                                                                          \
        float s4[2][4];                                                        \
        _Pragma("unroll")                                                      \
        for (int qq = 0; qq < 2; ++qq)                                         \
            *(float4*)(&s4[qq][0]) =                                           \
                *(const float4*)&sc_lds[(CC) & 1][w * 2 + qq][lane * 4];       \
        if ((CC) == 0) {                                                       \
            _Pragma("unroll")                                                  \
            for (int qq = 0; qq < 2; ++qq) {                                   \
                float lmax = NEGINF; int lslot = 0;                            \
                _Pragma("unroll")                                              \
                for (int j = 0; j < 4; ++j)                                    \
                    if (s4[qq][j] > lmax) { lmax = s4[qq][j]; lslot = j; }     \
                for (int it = 0; it < 32; ++it) {                              \
                    float wm = lmax;                                           \
                    _Pragma("unroll")                                          \
                    for (int off = 32; off; off >>= 1)                         \
                        wm = fmaxf(wm, __shfl_xor(wm, off));                   \
                    const unsigned long long bal = __ballot(lmax == wm);       \
                    const int winner = __ffsll((unsigned long long)bal) - 1;   \
                    const int wslot  = __shfl(lslot, winner);                  \
                    const int widx   = (winner << 2) + (wslot & 3);            \
                    const unsigned long long gb =                              \
                        __ballot((lane < K_) && (rv[qq] > wm));                \
                    const int pos = __popcll(gb);                              \
                    const float sv = __shfl_up(rv[qq], 1);                     \
                    const int   si = __shfl_up(rid_[qq], 1);                   \
                    if (lane > pos)       { rv[qq] = sv; rid_[qq] = si; }      \
                    else if (lane == pos) { rv[qq] = wm; rid_[qq] = widx; }    \
                    if (lane == winner) {                                      \
                        float nm = NEGINF; int ns = 0;                         \
                        _Pragma("unroll")                                      \
                        for (int j = 0; j < 4; ++j) {                          \
                            const float vj = (j == lslot) ? NEGINF : s4[qq][j];\
                            s4[qq][j] = vj;                                    \
                            if (vj > nm) { nm = vj; ns = j; }                  \
                        }                                                      \
                        lmax = nm; lslot = ns;                                 \
                    }                                                          \
                }                                                              \
                t32[qq] = __shfl(rv[qq], 31);                                  \
            }                                                                  \
        } else {                                                               \
            _Pragma("unroll")                                                  \
            for (int qq = 0; qq < 2; ++qq) {                                   \
                _Pragma("unroll")                                              \
                for (int j = 0; j < 4; ++j) {                                  \
                    unsigned long long bb = __ballot(s4[qq][j] > t32[qq]);     \
                    while (bb) {                                               \
                        const int L = __ffsll(bb) - 1;                         \
                        bb &= bb - 1;                                          \
                        const float xv = __shfl(s4[qq][j], L);                 \
                        const int xi = ((CC) << 8) + (L << 2) + j;             \
                        const unsigned long long gb =                          \
                            __ballot((lane < K_) && (rv[qq] > xv));            \
                        const int pos = __popcll(gb);                          \
                        const float sv = __shfl_up(rv[qq], 1);                 \
                        const int   si = __shfl_up(rid_[qq], 1);               \
                        if (lane > pos)       { rv[qq] = sv; rid_[qq] = si; }  \
                        else if (lane == pos) { rv[qq] = xv; rid_[qq] = xi; }  \
                    }                                                          \
                }                                                              \
                t32[qq] = __shfl(rv[qq], 31);                                  \
            }                                                                  \
        }                                                                      \
    }

    float rv[2];  int rid_[2];  float t32[2];
    #pragma unroll
    for (int qq = 0; qq < 2; ++qq) {
        rv[qq] = NEGINF; rid_[qq] = 0x7fffffff; t32[qq] = NEGINF;
    }

    short8_t khA[2][2], klA[2][2];   // named set A
    short8_t khB[2][2], klB[2][2];   // named set B

    // prologue: chunk 0 scored into buffer 0; chunk 1's fragments in flight (A)
    LOADFRAGS(0, khA, klA);
    MFMAWRITE(0, khA, klA);
    LOADFRAGS(1, khA, klA);
    __syncthreads();

    // steady state, unrolled by 2: at even c consume A / prefetch B, then swap
    for (int c = 0; c < 64; c += 2) {
        // even iteration: select c; MFMA chunk c+1 from A; prefetch c+2 into B
        if (c + 2 < 64) LOADFRAGS(c + 2, khB, klB);
        SELECT(c)
        if (c + 1 < 64) MFMAWRITE((c + 1) & 1, khA, klA);
        __syncthreads();
        // odd iteration: select c+1; MFMA chunk c+2 from B; prefetch c+3 into A
        if (c + 3 < 64) LOADFRAGS(c + 3, khA, klA);
        SELECT(c + 1)
        if (c + 2 < 64) MFMAWRITE((c + 2) & 1, khB, klB);
        __syncthreads();
    }

#undef LOADFRAGS
#undef MFMAWRITE
#undef SELECT

    // ---- epilogue: softmax over top-32, gather V, gated combine
    const float gv = gate[0];
    const float* vb = mem_vals + (size_t)b * N_ * D_;
    #pragma unroll
    for (int qq = 0; qq < 2; ++qq) {
        const float m = __shfl(rv[qq], 0);
        float wgt = (lane < K_) ? __expf((rv[qq] - m) * SCALE) : 0.f;
        float ssum = wgt;
        #pragma unroll
        for (int off = 32; off; off >>= 1) ssum += __shfl_xor(ssum, off);
        float acc = 0.f;
        for (int i = 0; i < K_; ++i) {
            const float wi = __shfl(wgt, i);
            const int   ii = __shfl(rid_[qq], i);
            acc += wi * vb[(size_t)ii * D_ + lane];
        }
        const size_t o = ((size_t)(b * T_ + t0 + w * 2 + qq)) * D_ + lane;
        outp[o] = outc[o] * gv + (acc / ssum) * (1.f - gv);
    }
}

extern "C" void kernel_launch(void* const* d_in, const int* in_sizes, int n_in,
                              void* d_out, int out_size, void* d_ws, size_t ws_size,
                              hipStream_t stream) {
    const float* x        = (const float*)d_in[0];
    const float* mem_keys = (const float*)d_in[1];
    const float* mem_vals = (const float*)d_in[2];
    const float* Wq       = (const float*)d_in[3];
    const float* bq       = (const float*)d_in[4];
    const float* Wk       = (const float*)d_in[5];
    const float* bk       = (const float*)d_in[6];
    const float* Wv       = (const float*)d_in[7];
    const float* bv       = (const float*)d_in[8];
    const float* gate     = (const float*)d_in[9];
    float* out = (float*)d_out;

    const size_t btd = (size_t)B_ * T_ * D_;   // 524288
    float* q    = (float*)d_ws;
    float* k    = q + btd;
    float* v    = k + btd;
    float* outc = v + btd;
    unsigned short* khi    = (unsigned short*)(outc + btd);   // 8 MB
    unsigned short* klo    = khi + (size_t)B_ * N_ * D_;      // 8 MB
    unsigned short* kcfrag = klo + (size_t)B_ * N_ * D_;      // 1 MB
    unsigned short* vfrag  = kcfrag + btd;                    // 1 MB
    unsigned short* whfrag = vfrag + btd;                     // 384 KB
    unsigned short* wlfrag = whfrag + (size_t)384 * 512;      // 384 KB

    wfrag_prep_kernel<<<96, 256, 0, stream>>>(Wq, Wk, Wv, whfrag, wlfrag);
    qkv_mfma_kernel<<<B_ * T_ / 32, 256, 0, stream>>>(x, whfrag, wlfrag,
                                                      bq, bk, bv, q, k, v);
    kfrag_prep_kernel<<<B_ * 512, 256, 0, stream>>>(mem_keys, khi, klo);
    causal_prep_kernel<<<B_ * 32, 256, 0, stream>>>(k, v, kcfrag, vfrag);
    causal_flash_kernel<<<B_ * 128, 256, 0, stream>>>(q, kcfrag, vfrag, outc);
    knn_mfma_kernel<<<512, 512, 0, stream>>>(q, khi, klo, mem_vals, outc, gate, out);
}